// Round 1
// baseline (508.375 us; speedup 1.0000x reference)
//
#include <hip/hip_runtime.h>
#include <math.h>

#define NROW 8192
#define IN_F 256
#define OUT_F 128
#define SLOPE 0.1f

__device__ __forceinline__ float lrelu(float x) { return x > 0.f ? x : SLOPE * x; }

// ---------------------------------------------------------------- k1: h = doc @ Ww^T + Wb
__global__ __launch_bounds__(256) void k1_h(const float* __restrict__ doc,
                                            const float* __restrict__ Ww,
                                            const float* __restrict__ Wb,
                                            float* __restrict__ h) {
    __shared__ float4 sdoc[16][64];  // 16 rows x 256 floats = 16KB
    const int t = threadIdx.x;
    const int rowBase = blockIdx.x * 16;
    const float4* doc4 = (const float4*)(doc + (size_t)rowBase * IN_F);
    float4* sflat = &sdoc[0][0];
    for (int i = t; i < 16 * 64; i += 256) sflat[i] = doc4[i];
    __syncthreads();
    const int c = t & 127;
    const int rg = t >> 7;
    float acc[8];
#pragma unroll
    for (int r = 0; r < 8; ++r) acc[r] = 0.f;
    const float4* w4 = (const float4*)(Ww + (size_t)c * IN_F);
    for (int k = 0; k < 64; ++k) {
        const float4 w = w4[k];
#pragma unroll
        for (int r = 0; r < 8; ++r) {
            const float4 d = sdoc[2 * r + rg][k];
            acc[r] += d.x * w.x + d.y * w.y + d.z * w.z + d.w * w.w;
        }
    }
    const float b = Wb[c];
#pragma unroll
    for (int r = 0; r < 8; ++r)
        h[(size_t)(rowBase + 2 * r + rg) * OUT_F + c] = acc[r] + b;
}

// ---------------------------------------------------------------- k1b: s_src, s_dst
__global__ __launch_bounds__(256) void k1b_sv(const float* __restrict__ h,
                                              const float* __restrict__ aw,
                                              float* __restrict__ s_src,
                                              float* __restrict__ s_dst) {
    const int wave = threadIdx.x >> 6, lane = threadIdx.x & 63;
    const int row = blockIdx.x * 4 + wave;
    const float2 hv = ((const float2*)(h + (size_t)row * OUT_F))[lane];
    const float2 as = ((const float2*)aw)[lane];
    const float2 ad = ((const float2*)(aw + OUT_F))[lane];
    float ps = hv.x * as.x + hv.y * as.y;
    float pd = hv.x * ad.x + hv.y * ad.y;
    for (int off = 32; off; off >>= 1) {
        ps += __shfl_down(ps, off);
        pd += __shfl_down(pd, off);
    }
    if (lane == 0) { s_src[row] = ps; s_dst[row] = pd; }
}

// ---------------------------------------------------------------- k2: top-2 max of s_dst (+argmax), E1/E2
__global__ __launch_bounds__(256) void k2_top2(const float* __restrict__ sdst,
                                               float* __restrict__ red,
                                               float* __restrict__ E1,
                                               float* __restrict__ E2) {
    const int t = threadIdx.x;
    float m1 = -1e30f, m2 = -1e30f; int i1 = 0;
    for (int j = t; j < NROW; j += 256) {
        const float v = sdst[j];
        E1[j] = expf(v);
        E2[j] = expf(SLOPE * v);
        if (v > m1) { m2 = m1; m1 = v; i1 = j; }
        else if (v > m2) { m2 = v; }
    }
    __shared__ float sm1[256], sm2[256];
    __shared__ int si[256];
    sm1[t] = m1; sm2[t] = m2; si[t] = i1;
    __syncthreads();
    for (int s = 128; s > 0; s >>= 1) {
        if (t < s) {
            const float om1 = sm1[t + s], om2 = sm2[t + s];
            const int oi = si[t + s];
            if (om1 > sm1[t]) {
                sm2[t] = fmaxf(sm1[t], om2);
                sm1[t] = om1; si[t] = oi;
            } else {
                sm2[t] = fmaxf(sm2[t], om1);
            }
        }
        __syncthreads();
    }
    if (t == 0) { red[0] = sm1[0]; red[1] = sm2[0]; red[2] = __int_as_float(si[0]); }
}

// ---------------------------------------------------------------- k2b: rank -> permutation (ascending s_dst)
__global__ __launch_bounds__(256) void k2b_rank(const float* __restrict__ sdst,
                                                int* __restrict__ perm) {
    __shared__ float sd[NROW];
    for (int j = threadIdx.x; j < NROW; j += 256) sd[j] = sdst[j];
    __syncthreads();
    const int wave = threadIdx.x >> 6, lane = threadIdx.x & 63;
    const int i = blockIdx.x * 4 + wave;
    const float si_v = sd[i];
    int cnt = 0;
    for (int j = lane; j < NROW; j += 64) {
        const float v = sd[j];
        cnt += (v < si_v || (v == si_v && j < i)) ? 1 : 0;
    }
    for (int off = 32; off; off >>= 1) cnt += __shfl_down(cnt, off);
    if (lane == 0) perm[cnt] = i;
}

// ---------------------------------------------------------------- k3a: gather into sorted order, scale by E1/E2
__global__ __launch_bounds__(256) void k3a_gather(const int* __restrict__ perm,
                                                  const float* __restrict__ E1,
                                                  const float* __restrict__ E2,
                                                  const float* __restrict__ sdst,
                                                  const float* __restrict__ h,
                                                  float* __restrict__ X1,
                                                  float* __restrict__ X2,
                                                  float* __restrict__ sortedS,
                                                  float* __restrict__ E1s,
                                                  float* __restrict__ E2s) {
    const int t = threadIdx.x;
    const int c = t & 127;
    const int half = t >> 7;
    const int base = blockIdx.x * 128;
    for (int rr = 0; rr < 64; ++rr) {
        const int r = base + rr * 2 + half;
        const int i = perm[r];
        const float hv = h[(size_t)i * OUT_F + c];
        X1[(size_t)r * OUT_F + c] = E1[i] * hv;
        X2[(size_t)r * OUT_F + c] = E2[i] * hv;
        if (c == 0) {
            sortedS[r] = sdst[i];
            E1s[r] = E1[i];
            E2s[r] = E2[i];
        }
    }
}

// ---------------------------------------------------------------- k3b1: per-segment column sums (64 segs of 128)
__global__ __launch_bounds__(256) void k3b1_segsum(const float* __restrict__ X1,
                                                   const float* __restrict__ X2,
                                                   float* __restrict__ seg1,
                                                   float* __restrict__ seg2) {
    const int tid = blockIdx.x * 256 + threadIdx.x;
    const int s = tid >> 7, c = tid & 127;
    float a = 0.f, b = 0.f;
    const int r0 = s * 128;
    for (int r = r0; r < r0 + 128; ++r) {
        a += X1[(size_t)r * OUT_F + c];
        b += X2[(size_t)r * OUT_F + c];
    }
    seg1[s * OUT_F + c] = a;
    seg2[s * OUT_F + c] = b;
}

// ---------------------------------------------------------------- k3b2: U = suffix-incl scan of X1; V = prefix-excl scan of X2
__global__ __launch_bounds__(256) void k3b2_scan(const float* __restrict__ X1,
                                                 const float* __restrict__ X2,
                                                 const float* __restrict__ seg1,
                                                 const float* __restrict__ seg2,
                                                 float* __restrict__ U,
                                                 float* __restrict__ V) {
    const int tid = blockIdx.x * 256 + threadIdx.x;
    const int s = tid >> 7, c = tid & 127;
    float offU = 0.f, offV = 0.f;
    for (int s2 = s + 1; s2 < 64; ++s2) offU += seg1[s2 * OUT_F + c];
    for (int s2 = 0; s2 < s; ++s2) offV += seg2[s2 * OUT_F + c];
    const int r0 = s * 128;
    float run = offU;
    for (int r = r0 + 127; r >= r0; --r) {
        run += X1[(size_t)r * OUT_F + c];
        U[(size_t)r * OUT_F + c] = run;
    }
    float rv = offV;
    for (int r = r0; r < r0 + 128; ++r) {
        V[(size_t)r * OUT_F + c] = rv;
        rv += X2[(size_t)r * OUT_F + c];
    }
    if (s == 0) U[(size_t)NROW * OUT_F + c] = 0.f;
    if (s == 63) V[(size_t)NROW * OUT_F + c] = rv;
}

// ---------------------------------------------------------------- k3c: scalar scans Psuf/Qpre of E1s/E2s
__global__ __launch_bounds__(256) void k3c_scalar(const float* __restrict__ E1s,
                                                  const float* __restrict__ E2s,
                                                  float* __restrict__ Psuf,
                                                  float* __restrict__ Qpre) {
    __shared__ float p1[256], p2[256];
    const int t = threadIdx.x;
    const int r0 = t * 32;
    float a = 0.f, b = 0.f;
    for (int r = r0; r < r0 + 32; ++r) { a += E1s[r]; b += E2s[r]; }
    p1[t] = a; p2[t] = b;
    __syncthreads();
    float offP = 0.f, offQ = 0.f;
    for (int t2 = t + 1; t2 < 256; ++t2) offP += p1[t2];
    for (int t2 = 0; t2 < t; ++t2) offQ += p2[t2];
    float run = offP;
    for (int r = r0 + 31; r >= r0; --r) { run += E1s[r]; Psuf[r] = run; }
    float rq = offQ;
    for (int r = r0; r < r0 + 32; ++r) { Qpre[r] = rq; rq += E2s[r]; }
    if (t == 0) Psuf[NROW] = 0.f;
    if (t == 255) Qpre[NROW] = rq;
}

// ---------------------------------------------------------------- k4pre: per-row A, B, Z, k, e_ii
__global__ __launch_bounds__(256) void k4pre(const float* __restrict__ s_src,
                                             const float* __restrict__ sdst,
                                             const float* __restrict__ sortedS,
                                             const float* __restrict__ Psuf,
                                             const float* __restrict__ Qpre,
                                             const float* __restrict__ red,
                                             const float* __restrict__ ab,
                                             const int* __restrict__ selfLink,
                                             float* __restrict__ A,
                                             float* __restrict__ B,
                                             float* __restrict__ rZ,
                                             float* __restrict__ Eii,
                                             float* __restrict__ Tarr,
                                             int* __restrict__ kidx) {
    const int i = blockIdx.x * 256 + threadIdx.x;
    const bool mask = (selfLink[0] == 0);
    const float t = s_src[i] + ab[0];
    const float M1 = red[0], M2 = red[1];
    const int i1 = __float_as_int(red[2]);
    const float M = (mask && i1 == i) ? M2 : M1;
    const float m = lrelu(t + M);
    const float Ai = expf(t - m);
    const float Bi = expf(SLOPE * t - m);
    const float eii = mask ? expf(lrelu(t + sdst[i]) - m) : 0.f;
    const float thr = -t;
    int lo = 0, hi = NROW;
    while (lo < hi) {
        const int mid = (lo + hi) >> 1;
        if (sortedS[mid] > thr) hi = mid; else lo = mid + 1;
    }
    const int k = lo;
    const float Z = Ai * Psuf[k] + Bi * Qpre[k] - eii;
    A[i] = Ai; B[i] = Bi; rZ[i] = 1.f / Z; Eii[i] = eii; Tarr[i] = t; kidx[i] = k;
}

// ---------------------------------------------------------------- k4a: h_out
__global__ __launch_bounds__(256) void k4a_hout(const float* __restrict__ A,
                                                const float* __restrict__ B,
                                                const float* __restrict__ rZ,
                                                const float* __restrict__ Eii,
                                                const int* __restrict__ kidx,
                                                const float* __restrict__ U,
                                                const float* __restrict__ V,
                                                const float* __restrict__ h,
                                                float* __restrict__ hout) {
    const int t = threadIdx.x;
    const int i = blockIdx.x * 2 + (t >> 7);
    const int c = t & 127;
    const int k = kidx[i];
    const float val = A[i] * U[(size_t)k * OUT_F + c] + B[i] * V[(size_t)k * OUT_F + c]
                    - Eii[i] * h[(size_t)i * OUT_F + c];
    hout[(size_t)i * OUT_F + c] = lrelu(val * rZ[i]);
}

// ---------------------------------------------------------------- k5: stream the att matrix (no exp in loop)
#define ROWS5 8
#define JCH 2048
__global__ __launch_bounds__(256) void k5_att(const float* __restrict__ sdst,
                                              const float* __restrict__ E1,
                                              const float* __restrict__ E2,
                                              const float* __restrict__ A,
                                              const float* __restrict__ B,
                                              const float* __restrict__ rZ,
                                              const float* __restrict__ Tarr,
                                              const int* __restrict__ selfLink,
                                              float* __restrict__ att) {
    __shared__ float4 sS[JCH / 4], sE1[JCH / 4], sE2[JCH / 4];
    __shared__ float rA[ROWS5], rB[ROWS5], rT[ROWS5];
    const int t = threadIdx.x;
    const int rowBase = blockIdx.x * ROWS5;
    const bool mask = (selfLink[0] == 0);
    if (t < ROWS5) {
        const int i = rowBase + t;
        const float z = rZ[i];
        rA[t] = A[i] * z;
        rB[t] = B[i] * z;
        rT[t] = -Tarr[i];
    }
    for (int ch = 0; ch < NROW; ch += JCH) {
        __syncthreads();
        for (int q = t; q < JCH / 4; q += 256) {
            sS[q]  = ((const float4*)(sdst + ch))[q];
            sE1[q] = ((const float4*)(E1 + ch))[q];
            sE2[q] = ((const float4*)(E2 + ch))[q];
        }
        __syncthreads();
        for (int r = 0; r < ROWS5; ++r) {
            const int i = rowBase + r;
            const float a = rA[r], b = rB[r], thr = rT[r];
            for (int q = t; q < JCH / 4; q += 256) {
                const float4 s4 = sS[q], e1 = sE1[q], e2 = sE2[q];
                float4 o;
                o.x = s4.x > thr ? a * e1.x : b * e2.x;
                o.y = s4.y > thr ? a * e1.y : b * e2.y;
                o.z = s4.z > thr ? a * e1.z : b * e2.z;
                o.w = s4.w > thr ? a * e1.w : b * e2.w;
                const int j0 = ch + q * 4;
                if (mask && i >= j0 && i < j0 + 4) ((float*)&o)[i - j0] = 0.f;
                ((float4*)(att + (size_t)i * NROW + ch))[q] = o;
            }
        }
    }
}

// ----------------------------------------------------------------
extern "C" void kernel_launch(void* const* d_in, const int* in_sizes, int n_in,
                              void* d_out, int out_size, void* d_ws, size_t ws_size,
                              hipStream_t stream) {
    const float* doc = (const float*)d_in[0];
    const float* Ww  = (const float*)d_in[1];
    const float* Wb  = (const float*)d_in[2];
    const float* aw  = (const float*)d_in[3];
    const float* ab  = (const float*)d_in[4];
    const int* selfLink = (const int*)d_in[5];

    float* out  = (float*)d_out;
    float* hout = out;                                   // NROW*OUT_F
    float* att  = out + (size_t)NROW * OUT_F;            // NROW*NROW

    // Big scratch lives inside the att output region (all consumers run before k5 overwrites it)
    float* h  = att;
    float* X1 = att + 1048576;
    float* X2 = att + 2097152;
    float* U  = att + 3145728;   // (NROW+1) x OUT_F
    float* V  = att + 4194432;   // (NROW+1) x OUT_F

    float* ws = (float*)d_ws;
    float* s_src   = ws;
    float* s_dst   = ws + 8192;
    float* E1      = ws + 16384;
    float* E2      = ws + 24576;
    float* sortedS = ws + 32768;
    float* E1s     = ws + 40960;
    float* E2s     = ws + 49152;
    float* Aarr    = ws + 57344;
    float* Barr    = ws + 65536;
    float* rZ      = ws + 73728;
    float* Eii     = ws + 81920;
    float* Tarr    = ws + 90112;
    int*   perm    = (int*)(ws + 98304);
    int*   kidx    = (int*)(ws + 106496);
    float* seg1    = ws + 114688;
    float* seg2    = ws + 122880;
    float* Psuf    = ws + 131072;  // 8193 (padded)
    float* Qpre    = ws + 139272;  // 8193 (padded)
    float* red     = ws + 147472;  // M1, M2, argmax-bits

    k1_h   <<<512,  256, 0, stream>>>(doc, Ww, Wb, h);
    k1b_sv <<<2048, 256, 0, stream>>>(h, aw, s_src, s_dst);
    k2_top2<<<1,    256, 0, stream>>>(s_dst, red, E1, E2);
    k2b_rank<<<2048,256, 0, stream>>>(s_dst, perm);
    k3a_gather<<<64,256, 0, stream>>>(perm, E1, E2, s_dst, h, X1, X2, sortedS, E1s, E2s);
    k3b1_segsum<<<32,256,0, stream>>>(X1, X2, seg1, seg2);
    k3b2_scan<<<32, 256, 0, stream>>>(X1, X2, seg1, seg2, U, V);
    k3c_scalar<<<1, 256, 0, stream>>>(E1s, E2s, Psuf, Qpre);
    k4pre  <<<32,   256, 0, stream>>>(s_src, s_dst, sortedS, Psuf, Qpre, red, ab, selfLink,
                                      Aarr, Barr, rZ, Eii, Tarr, kidx);
    k4a_hout<<<4096,256, 0, stream>>>(Aarr, Barr, rZ, Eii, kidx, U, V, h, hout);
    k5_att <<<1024, 256, 0, stream>>>(s_dst, E1, E2, Aarr, Barr, rZ, Tarr, selfLink, att);
}

// Round 2
// 453.203 us; speedup vs baseline: 1.1217x; 1.1217x over previous
//
#include <hip/hip_runtime.h>
#include <math.h>

#define NROW 8192
#define IN_F 256
#define OUT_F 128
#define SLOPE 0.1f
#define SEGS 256          // 256 segments x 32 rows
#define SEGROWS 32

__device__ __forceinline__ float lrelu(float x) { return x > 0.f ? x : SLOPE * x; }

// ---------------------------------------------------------------- kA: h = doc@Ww^T + Wb, plus s_src/s_dst/E1/E2 per row
__global__ __launch_bounds__(256) void kA_h_s(const float* __restrict__ doc,
                                              const float* __restrict__ Ww,
                                              const float* __restrict__ Wb,
                                              const float* __restrict__ aw,
                                              float* __restrict__ h,
                                              float* __restrict__ s_src,
                                              float* __restrict__ s_dst,
                                              float* __restrict__ E1,
                                              float* __restrict__ E2) {
    __shared__ float4 sdoc[16][64];  // 16 rows x 256 floats = 16KB
    __shared__ float sred[4][8][2];  // wave, r, {src,dst}
    const int t = threadIdx.x;
    const int rowBase = blockIdx.x * 16;
    const float4* doc4 = (const float4*)(doc + (size_t)rowBase * IN_F);
    float4* sflat = &sdoc[0][0];
    for (int i = t; i < 16 * 64; i += 256) sflat[i] = doc4[i];
    __syncthreads();
    const int c = t & 127;
    const int rg = t >> 7;           // waves {0,1}->rg0, {2,3}->rg1
    float acc[8];
#pragma unroll
    for (int r = 0; r < 8; ++r) acc[r] = 0.f;
    const float4* w4 = (const float4*)(Ww + (size_t)c * IN_F);
    for (int k = 0; k < 64; ++k) {
        const float4 w = w4[k];
#pragma unroll
        for (int r = 0; r < 8; ++r) {
            const float4 d = sdoc[2 * r + rg][k];
            acc[r] += d.x * w.x + d.y * w.y + d.z * w.z + d.w * w.w;
        }
    }
    const float b = Wb[c];
    const float asrc = aw[c];
    const float adst = aw[OUT_F + c];
    const int wave = t >> 6;
    const int lane = t & 63;
#pragma unroll
    for (int r = 0; r < 8; ++r) {
        const float hv = acc[r] + b;
        h[(size_t)(rowBase + 2 * r + rg) * OUT_F + c] = hv;
        float ps = hv * asrc;
        float pd = hv * adst;
        for (int off = 32; off; off >>= 1) {
            ps += __shfl_down(ps, off);
            pd += __shfl_down(pd, off);
        }
        if (lane == 0) { sred[wave][r][0] = ps; sred[wave][r][1] = pd; }
    }
    __syncthreads();
    if (t < 32) {
        const int r = t >> 2;
        const int rem = t & 3;
        const int rg2 = rem >> 1;
        const int which = rem & 1;
        const float val = sred[2 * rg2][r][which] + sred[2 * rg2 + 1][r][which];
        const int row = rowBase + 2 * r + rg2;
        if (which == 0) {
            s_src[row] = val;
        } else {
            s_dst[row] = val;
            E1[row] = expf(val);
            E2[row] = expf(SLOPE * val);
        }
    }
}

// ---------------------------------------------------------------- kB: top-2 max of s_dst (+argmax)
__global__ __launch_bounds__(256) void kB_top2(const float* __restrict__ sdst,
                                               float* __restrict__ red) {
    const int t = threadIdx.x;
    float m1 = -1e30f, m2 = -1e30f; int i1 = 0;
    for (int j = t; j < NROW; j += 256) {
        const float v = sdst[j];
        if (v > m1) { m2 = m1; m1 = v; i1 = j; }
        else if (v > m2) { m2 = v; }
    }
    __shared__ float sm1[256], sm2[256];
    __shared__ int si[256];
    sm1[t] = m1; sm2[t] = m2; si[t] = i1;
    __syncthreads();
    for (int s = 128; s > 0; s >>= 1) {
        if (t < s) {
            const float om1 = sm1[t + s], om2 = sm2[t + s];
            const int oi = si[t + s];
            if (om1 > sm1[t]) {
                sm2[t] = fmaxf(sm1[t], om2);
                sm1[t] = om1; si[t] = oi;
            } else {
                sm2[t] = fmaxf(sm2[t], om1);
            }
        }
        __syncthreads();
    }
    if (t == 0) { red[0] = sm1[0]; red[1] = sm2[0]; red[2] = __int_as_float(si[0]); }
}

// ---------------------------------------------------------------- kC: rank -> permutation (ascending s_dst), 32 rows/block
__global__ __launch_bounds__(256) void kC_rank(const float* __restrict__ sdst,
                                               int* __restrict__ perm) {
    __shared__ float sd[NROW];       // 32 KB
    {
        float4* sd4 = (float4*)sd;
        const float4* g4 = (const float4*)sdst;
        for (int q = threadIdx.x; q < NROW / 4; q += 256) sd4[q] = g4[q];
    }
    __syncthreads();
    const int wave = threadIdx.x >> 6, lane = threadIdx.x & 63;
    const int base = blockIdx.x * 32 + wave * 8;
    float rv[8]; int ri[8]; int cnt[8];
#pragma unroll
    for (int r = 0; r < 8; ++r) { ri[r] = base + r; rv[r] = sd[ri[r]]; cnt[r] = 0; }
    for (int j = lane; j < NROW; j += 64) {
        const float v = sd[j];
#pragma unroll
        for (int r = 0; r < 8; ++r)
            cnt[r] += (v < rv[r] || (v == rv[r] && j < ri[r])) ? 1 : 0;
    }
#pragma unroll
    for (int r = 0; r < 8; ++r)
        for (int off = 32; off; off >>= 1) cnt[r] += __shfl_down(cnt[r], off);
    if (lane == 0) {
#pragma unroll
        for (int r = 0; r < 8; ++r) perm[cnt[r]] = ri[r];
    }
}

// ---------------------------------------------------------------- kD: gather sortedS/E1s/E2s + per-segment column sums
__global__ __launch_bounds__(256) void kD_gseg(const int* __restrict__ perm,
                                               const float* __restrict__ E1,
                                               const float* __restrict__ E2,
                                               const float* __restrict__ sdst,
                                               const float* __restrict__ h,
                                               float* __restrict__ sortedS,
                                               float* __restrict__ E1s,
                                               float* __restrict__ E2s,
                                               float* __restrict__ seg1,
                                               float* __restrict__ seg2) {
    __shared__ float part[2][4][128][2];  // half, seg, col, arr = 8 KB
    const int t = threadIdx.x;
    const int c = t & 127;
    const int half = t >> 7;
    const int base = blockIdx.x * 128;
    float a1[4] = {0.f, 0.f, 0.f, 0.f};
    float a2[4] = {0.f, 0.f, 0.f, 0.f};
#pragma unroll
    for (int s = 0; s < 4; ++s) {
        for (int rr2 = 0; rr2 < 16; ++rr2) {
            const int rr = s * 16 + rr2;
            const int lr = rr * 2 + half;       // local row 0..127, seg(lr)==s
            const int r = base + lr;
            const int i = perm[r];
            const float hv = h[(size_t)i * OUT_F + c];
            const float e1 = E1[i];
            const float e2 = E2[i];
            a1[s] += e1 * hv;
            a2[s] += e2 * hv;
            if (c == 0) { sortedS[r] = sdst[i]; E1s[r] = e1; E2s[r] = e2; }
        }
        part[half][s][c][0] = a1[s];
        part[half][s][c][1] = a2[s];
    }
    __syncthreads();
    const int idx4 = t * 4;
#pragma unroll
    for (int q = 0; q < 4; ++q) {
        const int idx = idx4 + q;               // 0..1023
        const int arr = idx & 1;
        const int c2 = (idx >> 1) & 127;
        const int s2 = idx >> 8;
        const float v = part[0][s2][c2][arr] + part[1][s2][c2][arr];
        float* dst = arr ? seg2 : seg1;
        dst[(size_t)(blockIdx.x * 4 + s2) * OUT_F + c2] = v;
    }
}

// ---------------------------------------------------------------- kE: blocks 0..255 -> seg offset scans; 256 -> Psuf; 257 -> Qpre
__global__ __launch_bounds__(256) void kE_scan(const float* __restrict__ seg1,
                                               const float* __restrict__ seg2,
                                               const float* __restrict__ E1s,
                                               const float* __restrict__ E2s,
                                               float* __restrict__ segUo,
                                               float* __restrict__ segVo,
                                               float* __restrict__ Psuf,
                                               float* __restrict__ Qpre) {
    const int p = blockIdx.x;
    const int t = threadIdx.x;
    if (p < 256) {
        const int arr = p >> 7;       // 0: seg1 suffix-excl, 1: seg2 prefix-excl
        const int col = p & 127;
        const float* src = arr ? seg2 : seg1;
        const float x = src[(size_t)t * OUT_F + col];
        __shared__ float buf[256];
        const int j = arr ? t : (255 - t);   // reverse for suffix scan
        buf[j] = x;
        __syncthreads();
        for (int off = 1; off < 256; off <<= 1) {
            const float add = (j >= off) ? buf[j - off] : 0.f;
            __syncthreads();
            buf[j] += add;
            __syncthreads();
        }
        const float excl = buf[j] - x;
        float* dst = arr ? segVo : segUo;
        dst[(size_t)t * OUT_F + col] = excl;
    } else if (p == 256) {
        // Psuf: suffix-inclusive scan of E1s, Psuf[NROW]=0
        __shared__ float pp[256];
        const int r0 = t * 32;
        float a = 0.f;
        for (int rr = 0; rr < 32; ++rr) a += E1s[r0 + rr];
        pp[t] = a;
        __syncthreads();
        float off = 0.f;
        for (int t2 = t + 1; t2 < 256; ++t2) off += pp[t2];
        float run = off;
        for (int rr = 31; rr >= 0; --rr) { run += E1s[r0 + rr]; Psuf[r0 + rr] = run; }
        if (t == 0) Psuf[NROW] = 0.f;
    } else {
        // Qpre: prefix-exclusive scan of E2s, Qpre[NROW]=total
        __shared__ float pp[256];
        const int r0 = t * 32;
        float a = 0.f;
        for (int rr = 0; rr < 32; ++rr) a += E2s[r0 + rr];
        pp[t] = a;
        __syncthreads();
        float off = 0.f;
        for (int t2 = 0; t2 < t; ++t2) off += pp[t2];
        float rv = off;
        for (int rr = 0; rr < 32; ++rr) { Qpre[r0 + rr] = rv; rv += E2s[r0 + rr]; }
        if (t == 255) Qpre[NROW] = rv;
    }
}

// ---------------------------------------------------------------- kF: U (suffix-incl of E1s*h) and V (prefix-excl of E2s*h)
__global__ __launch_bounds__(256) void kF_uv(const int* __restrict__ perm,
                                             const float* __restrict__ h,
                                             const float* __restrict__ E1s,
                                             const float* __restrict__ E2s,
                                             const float* __restrict__ segUo,
                                             const float* __restrict__ segVo,
                                             float* __restrict__ U,
                                             float* __restrict__ V) {
    const int t = threadIdx.x;
    const int half = t >> 7;
    const int c = t & 127;
    const int s = blockIdx.x * 2 + half;    // 0..255
    const int r0 = s * SEGROWS;
    float xv[SEGROWS];
#pragma unroll
    for (int rr = 0; rr < SEGROWS; ++rr) {
        const int i = perm[r0 + rr];
        xv[rr] = h[(size_t)i * OUT_F + c];
    }
    float run = segUo[(size_t)s * OUT_F + c];
#pragma unroll
    for (int rr = SEGROWS - 1; rr >= 0; --rr) {
        run += E1s[r0 + rr] * xv[rr];
        U[(size_t)(r0 + rr) * OUT_F + c] = run;
    }
    float rv = segVo[(size_t)s * OUT_F + c];
#pragma unroll
    for (int rr = 0; rr < SEGROWS; ++rr) {
        V[(size_t)(r0 + rr) * OUT_F + c] = rv;
        rv += E2s[r0 + rr] * xv[rr];
    }
    if (s == SEGS - 1) {
        U[(size_t)NROW * OUT_F + c] = 0.f;
        V[(size_t)NROW * OUT_F + c] = rv;
    }
}

// ---------------------------------------------------------------- kG: row constants (A,B,rZ,T) + h_out
__global__ __launch_bounds__(256) void kG_hout(const float* __restrict__ s_src,
                                               const float* __restrict__ sdst,
                                               const float* __restrict__ sortedS,
                                               const float* __restrict__ Psuf,
                                               const float* __restrict__ Qpre,
                                               const float* __restrict__ red,
                                               const float* __restrict__ ab,
                                               const int* __restrict__ selfLink,
                                               const float* __restrict__ U,
                                               const float* __restrict__ V,
                                               const float* __restrict__ h,
                                               float* __restrict__ A,
                                               float* __restrict__ B,
                                               float* __restrict__ rZ,
                                               float* __restrict__ T,
                                               float* __restrict__ hout) {
    const int t = threadIdx.x;
    const int i = blockIdx.x * 2 + (t >> 7);
    const int c = t & 127;
    const bool mask = (selfLink[0] == 0);
    const float tt = s_src[i] + ab[0];
    const float M1 = red[0], M2 = red[1];
    const int i1 = __float_as_int(red[2]);
    const float M = (mask && i1 == i) ? M2 : M1;
    const float m = lrelu(tt + M);
    const float Ai = expf(tt - m);
    const float Bi = expf(SLOPE * tt - m);
    const float eii = mask ? expf(lrelu(tt + sdst[i]) - m) : 0.f;
    const float thr = -tt;
    int lo = 0, hi = NROW;
    while (lo < hi) {
        const int mid = (lo + hi) >> 1;
        if (sortedS[mid] > thr) hi = mid; else lo = mid + 1;
    }
    const int k = lo;
    const float Z = Ai * Psuf[k] + Bi * Qpre[k] - eii;
    const float rZi = 1.f / Z;
    const float val = Ai * U[(size_t)k * OUT_F + c] + Bi * V[(size_t)k * OUT_F + c]
                    - eii * h[(size_t)i * OUT_F + c];
    hout[(size_t)i * OUT_F + c] = lrelu(val * rZi);
    if (c == 0) { A[i] = Ai; B[i] = Bi; rZ[i] = rZi; T[i] = tt; }
}

// ---------------------------------------------------------------- kH: stream the att matrix (no exp in loop)
#define ROWS5 8
#define JCH 2048
__global__ __launch_bounds__(256) void kH_att(const float* __restrict__ sdst,
                                              const float* __restrict__ E1,
                                              const float* __restrict__ E2,
                                              const float* __restrict__ A,
                                              const float* __restrict__ B,
                                              const float* __restrict__ rZ,
                                              const float* __restrict__ T,
                                              const int* __restrict__ selfLink,
                                              float* __restrict__ att) {
    __shared__ float4 sS[JCH / 4], sE1[JCH / 4], sE2[JCH / 4];
    __shared__ float rA[ROWS5], rB[ROWS5], rT[ROWS5];
    const int t = threadIdx.x;
    const int rowBase = blockIdx.x * ROWS5;
    const bool mask = (selfLink[0] == 0);
    if (t < ROWS5) {
        const int i = rowBase + t;
        const float z = rZ[i];
        rA[t] = A[i] * z;
        rB[t] = B[i] * z;
        rT[t] = -T[i];
    }
    for (int ch = 0; ch < NROW; ch += JCH) {
        __syncthreads();
        for (int q = t; q < JCH / 4; q += 256) {
            sS[q]  = ((const float4*)(sdst + ch))[q];
            sE1[q] = ((const float4*)(E1 + ch))[q];
            sE2[q] = ((const float4*)(E2 + ch))[q];
        }
        __syncthreads();
        for (int r = 0; r < ROWS5; ++r) {
            const int i = rowBase + r;
            const float a = rA[r], b = rB[r], thr = rT[r];
            for (int q = t; q < JCH / 4; q += 256) {
                const float4 s4 = sS[q], e1 = sE1[q], e2 = sE2[q];
                float4 o;
                o.x = s4.x > thr ? a * e1.x : b * e2.x;
                o.y = s4.y > thr ? a * e1.y : b * e2.y;
                o.z = s4.z > thr ? a * e1.z : b * e2.z;
                o.w = s4.w > thr ? a * e1.w : b * e2.w;
                const int j0 = ch + q * 4;
                if (mask && i >= j0 && i < j0 + 4) ((float*)&o)[i - j0] = 0.f;
                ((float4*)(att + (size_t)i * NROW + ch))[q] = o;
            }
        }
    }
}

// ----------------------------------------------------------------
extern "C" void kernel_launch(void* const* d_in, const int* in_sizes, int n_in,
                              void* d_out, int out_size, void* d_ws, size_t ws_size,
                              hipStream_t stream) {
    const float* doc = (const float*)d_in[0];
    const float* Ww  = (const float*)d_in[1];
    const float* Wb  = (const float*)d_in[2];
    const float* aw  = (const float*)d_in[3];
    const float* ab  = (const float*)d_in[4];
    const int* selfLink = (const int*)d_in[5];

    float* out  = (float*)d_out;
    float* hout = out;                                   // NROW*OUT_F
    float* att  = out + (size_t)NROW * OUT_F;            // NROW*NROW

    // Big scratch (h, U, V) lives inside the att output region: every consumer
    // runs before kH overwrites it. 12.6 MB << 268 MB.
    float* h = att;                                      // NROW*OUT_F
    float* U = att + 1048576;                            // (NROW+1)*OUT_F
    float* V = att + 1048576 + 1048704;                  // (NROW+1)*OUT_F

    float* ws = (float*)d_ws;
    float* s_src   = ws;            // 8192
    float* s_dst   = ws + 8192;     // 8192
    float* E1      = ws + 16384;    // 8192
    float* E2      = ws + 24576;    // 8192
    float* sortedS = ws + 32768;    // 8192
    float* E1s     = ws + 40960;    // 8192
    float* E2s     = ws + 49152;    // 8192
    float* Aarr    = ws + 57344;    // 8192
    float* Barr    = ws + 65536;    // 8192
    float* rZ      = ws + 73728;    // 8192
    float* Tarr    = ws + 81920;    // 8192
    int*   perm    = (int*)(ws + 90112);   // 8192
    float* seg1    = ws + 98304;    // SEGS*OUT_F = 32768
    float* seg2    = ws + 131072;   // 32768
    float* segUo   = ws + 163840;   // 32768
    float* segVo   = ws + 196608;   // 32768
    float* Psuf    = ws + 229376;   // 8193
    float* Qpre    = ws + 237632;   // 8193
    float* red     = ws + 245888;   // 3

    kA_h_s <<<512,  256, 0, stream>>>(doc, Ww, Wb, aw, h, s_src, s_dst, E1, E2);
    kB_top2<<<1,    256, 0, stream>>>(s_dst, red);
    kC_rank<<<256,  256, 0, stream>>>(s_dst, perm);
    kD_gseg<<<64,   256, 0, stream>>>(perm, E1, E2, s_dst, h, sortedS, E1s, E2s, seg1, seg2);
    kE_scan<<<258,  256, 0, stream>>>(seg1, seg2, E1s, E2s, segUo, segVo, Psuf, Qpre);
    kF_uv  <<<128,  256, 0, stream>>>(perm, h, E1s, E2s, segUo, segVo, U, V);
    kG_hout<<<4096, 256, 0, stream>>>(s_src, s_dst, sortedS, Psuf, Qpre, red, ab, selfLink,
                                      U, V, h, Aarr, Barr, rZ, Tarr, hout);
    kH_att <<<1024, 256, 0, stream>>>(s_dst, E1, E2, Aarr, Barr, rZ, Tarr, selfLink, att);
}